// Round 4
// baseline (248.640 us; speedup 1.0000x reference)
//
#include <hip/hip_runtime.h>
#include <math.h>

#define B_ 2
#define L_ 512
#define V_ 64
#define D_ 128
#define NC_ 8
#define SCALE 0.08838834764831845f  // 1/sqrt(128)

#define THREADS 128
#define IT 64          // i rows per block tile (4 rows per thread)
#define JT 8           // j per tile
#define MAXIT (L_ / IT)

// DPP butterfly sum within aligned 8-lane groups: xor1, xor2, xor7 (all VALU,
// no LDS pipe -- __shfl_xor would emit ds_bpermute on the LDS pipe).
__device__ __forceinline__ float dpp8_sum(float x) {
  x += __int_as_float(__builtin_amdgcn_mov_dpp(__float_as_int(x), 0xB1, 0xF, 0xF, true));  // quad_perm [1,0,3,2] = xor1
  x += __int_as_float(__builtin_amdgcn_mov_dpp(__float_as_int(x), 0x4E, 0xF, 0xF, true));  // quad_perm [2,3,0,1] = xor2
  x += __int_as_float(__builtin_amdgcn_mov_dpp(__float_as_int(x), 0x141, 0xF, 0xF, true)); // row_half_mirror = xor7
  return x;
}

// ---------------- Kernel A: per-(b,cluster) member lists (deterministic) ----
__global__ __launch_bounds__(L_) void cluster_index_kernel(
    const int* __restrict__ label, int* __restrict__ counts, int* __restrict__ jlist) {
  int b = blockIdx.x;
  int tid = threadIdx.x;
  __shared__ int lab[L_];
  lab[tid] = label[b * L_ + tid];
  if (tid < NC_) counts[b * NC_ + tid] = 0;
  __syncthreads();
  int my = lab[tid];
  int rank = 0, cnt = 0;
  for (int j = 0; j < L_; ++j) {
    int e = (lab[j] == my) ? 1 : 0;
    cnt += e;
    if (j < tid) rank += e;
  }
  jlist[(b * NC_ + my) * L_ + rank] = tid;
  if (rank == 0) counts[b * NC_ + my] = cnt;
}

// ---------------- Kernel B: S[b,j,d] = sum_v key[b,j,v,d] -------------------
__global__ __launch_bounds__(256) void sumkey_kernel(
    const float* __restrict__ key, float* __restrict__ S) {
  int idx = blockIdx.x * 256 + threadIdx.x;  // over B_*L_*D_ = 131072
  int d = idx & (D_ - 1);
  int bj = idx >> 7;
  const float* kp = key + (size_t)bj * V_ * D_ + d;
  float s = 0.f;
#pragma unroll 8
  for (int v = 0; v < V_; ++v) s += kp[v * D_];
  S[idx] = s;
}

// ---------------- Kernel C: clustered flash attention -----------------------
// block = (b, c, k, itile of 64 rows). 128 threads = 8 dh x 16 slots; each
// thread owns D-eighth (4 interleaved float4 chunks dh+8t) x 4 i-rows
// (sl, sl+16, sl+32, sl+48). Every ds_read_b128 of S_t/V_t feeds 16 FMAs
// (4 rows x float4) -> 4x less LDS traffic than 1-row mapping. Reads are
// 8 distinct addresses/wave (broadcast x8), conflict-free.
__global__ __launch_bounds__(THREADS, 2) void clustered_attn_kernel(
    const float* __restrict__ q, const float* __restrict__ value,
    const float* __restrict__ S, const int* __restrict__ counts,
    const int* __restrict__ jlist, float* __restrict__ out) {
  int bid = blockIdx.x;
  int k = bid & (V_ - 1);
  int c = (bid >> 6) & (NC_ - 1);
  int b = (bid >> 9) & (B_ - 1);
  int itile = bid >> 10;
  int n = counts[b * NC_ + c];
  int it0 = itile * IT;
  if (it0 >= n) return;

  int tid = threadIdx.x;
  int dh = tid & 7;       // d-eighth
  int sl = tid >> 3;      // row slot 0..15

  __shared__ int jl[L_];              // 2 KB
  __shared__ float S_t[JT][D_];       // 4 KB
  __shared__ float V_t[JT][D_];       // 4 KB

  for (int j = tid; j < n; j += THREADS) jl[j] = jlist[(b * NC_ + c) * L_ + j];
  __syncthreads();

  bool act[4];
  float4 q4[4][4];
#pragma unroll
  for (int r = 0; r < 4; ++r) {
    int row = it0 + sl + 16 * r;
    act[r] = row < n;
    int i = jl[act[r] ? row : it0];
    const float* qrow = q + (size_t)((b * L_ + i) * V_ + k) * D_;
#pragma unroll
    for (int t = 0; t < 4; ++t)
      q4[r][t] = *(const float4*)(qrow + (dh + 8 * t) * 4);
  }

  float4 acc4[4][4];
#pragma unroll
  for (int r = 0; r < 4; ++r)
#pragma unroll
    for (int t = 0; t < 4; ++t) acc4[r][t] = make_float4(0.f, 0.f, 0.f, 0.f);
  float m[4], l[4];
#pragma unroll
  for (int r = 0; r < 4; ++r) { m[r] = -INFINITY; l[r] = 0.f; }

  const float4* S_t4 = (const float4*)&S_t[0][0];
  const float4* V_t4 = (const float4*)&V_t[0][0];

  for (int jt0 = 0; jt0 < n; jt0 += JT) {
    int jn = min(JT, n - jt0);
    __syncthreads();
    // stage S and V tiles: JT rows x 32 float4 each = 256 f4 per array
#pragma unroll
    for (int rep = 0; rep < 2; ++rep) {
      int idx = tid + rep * THREADS;
      int jj = idx >> 5;
      int d4 = idx & 31;
      int j = jl[jt0 + min(jj, jn - 1)];
      size_t rowbase = (size_t)(b * L_ + j);
      ((float4*)&S_t[0][0])[idx] = *(const float4*)(S + rowbase * D_ + d4 * 4);
      ((float4*)&V_t[0][0])[idx] =
          *(const float4*)(value + (rowbase * V_ + k) * D_ + d4 * 4);
    }
    __syncthreads();

    // ---- dot: s[r][jj] = q[r] . S[jj]  (partial over this d-eighth) ----
    float s[4][JT];
#pragma unroll
    for (int r = 0; r < 4; ++r)
#pragma unroll
      for (int jj = 0; jj < JT; ++jj) s[r][jj] = 0.f;
#pragma unroll
    for (int t = 0; t < 4; ++t) {
#pragma unroll
      for (int jj = 0; jj < JT; ++jj) {
        float4 sv = S_t4[jj * 32 + dh + 8 * t];
#pragma unroll
        for (int r = 0; r < 4; ++r) {
          float4 qv = q4[r][t];
          s[r][jj] = fmaf(qv.x, sv.x,
                     fmaf(qv.y, sv.y,
                     fmaf(qv.z, sv.z, fmaf(qv.w, sv.w, s[r][jj]))));
        }
      }
    }
    // reduce the 8 d-eighths (DPP, VALU pipe), scale
#pragma unroll
    for (int r = 0; r < 4; ++r)
#pragma unroll
      for (int jj = 0; jj < JT; ++jj)
        s[r][jj] = dpp8_sum(s[r][jj]) * SCALE;

    // ---- online softmax (branchless rescale) ----
#pragma unroll
    for (int r = 0; r < 4; ++r) {
      float mnew = m[r];
#pragma unroll
      for (int jj = 0; jj < JT; ++jj)
        if (jj < jn) mnew = fmaxf(mnew, s[r][jj]);
      float f = __expf(m[r] - mnew);  // m=-inf first tile -> f=0
      m[r] = mnew;
#pragma unroll
      for (int t = 0; t < 4; ++t) {
        acc4[r][t].x *= f; acc4[r][t].y *= f;
        acc4[r][t].z *= f; acc4[r][t].w *= f;
      }
      float sum = 0.f;
#pragma unroll
      for (int jj = 0; jj < JT; ++jj) {
        float p = (jj < jn) ? __expf(s[r][jj] - mnew) : 0.f;
        s[r][jj] = p;
        sum += p;
      }
      l[r] = l[r] * f + sum;
    }

    // ---- PV: acc[r] += p[r][jj] * V[jj] ----
#pragma unroll
    for (int t = 0; t < 4; ++t) {
#pragma unroll
      for (int jj = 0; jj < JT; ++jj) {
        float4 vv = V_t4[jj * 32 + dh + 8 * t];
#pragma unroll
        for (int r = 0; r < 4; ++r) {
          float p = s[r][jj];
          acc4[r][t].x = fmaf(p, vv.x, acc4[r][t].x);
          acc4[r][t].y = fmaf(p, vv.y, acc4[r][t].y);
          acc4[r][t].z = fmaf(p, vv.z, acc4[r][t].z);
          acc4[r][t].w = fmaf(p, vv.w, acc4[r][t].w);
        }
      }
    }
  }

#pragma unroll
  for (int r = 0; r < 4; ++r) {
    if (act[r]) {
      int i = jl[it0 + sl + 16 * r];
      float inv = 1.0f / l[r];
      float* op = out + (size_t)((b * L_ + i) * V_ + k) * D_;
#pragma unroll
      for (int t = 0; t < 4; ++t) {
        float4 o;
        o.x = acc4[r][t].x * inv;
        o.y = acc4[r][t].y * inv;
        o.z = acc4[r][t].z * inv;
        o.w = acc4[r][t].w * inv;
        *(float4*)(op + (dh + 8 * t) * 4) = o;
      }
    }
  }
}

extern "C" void kernel_launch(void* const* d_in, const int* in_sizes, int n_in,
                              void* d_out, int out_size, void* d_ws, size_t ws_size,
                              hipStream_t stream) {
  const float* q = (const float*)d_in[0];
  const float* key = (const float*)d_in[1];
  const float* value = (const float*)d_in[2];
  const int* label = (const int*)d_in[3];
  float* out = (float*)d_out;

  int* counts = (int*)d_ws;
  int* jlist = (int*)((char*)d_ws + 256);
  float* S = (float*)((char*)d_ws + 256 + B_ * NC_ * L_ * sizeof(int));

  cluster_index_kernel<<<B_, L_, 0, stream>>>(label, counts, jlist);
  sumkey_kernel<<<(B_ * L_ * D_) / 256, 256, 0, stream>>>(key, S);
  clustered_attn_kernel<<<B_ * NC_ * V_ * MAXIT, THREADS, 0, stream>>>(
      q, value, S, counts, jlist, out);
}

// Round 7
// 208.675 us; speedup vs baseline: 1.1915x; 1.1915x over previous
//
#include <hip/hip_runtime.h>
#include <math.h>

#define B_ 2
#define L_ 512
#define V_ 64
#define D_ 128
#define NC_ 8
#define NMAX 128
#define NPAD 8
#define SCALE 0.08838834764831845f  // 1/sqrt(128)

#define FB_THREADS 128
#define FB_IT 64
#define FB_JT 8
#define MAXIT (L_ / FB_IT)

typedef short s16x8 __attribute__((ext_vector_type(8)));
typedef float f32x4 __attribute__((ext_vector_type(4)));

__device__ __forceinline__ unsigned short f2bf(float x) {
  unsigned int u = __float_as_uint(x);
  u += 0x7FFFu + ((u >> 16) & 1u);
  return (unsigned short)(u >> 16);
}
__device__ __forceinline__ float bf2f(unsigned short h) {
  return __uint_as_float((unsigned int)h << 16);
}

// ---------------- Kernel A: per-(b,cluster) member lists (deterministic) ----
__global__ __launch_bounds__(L_) void cluster_index_kernel(
    const int* __restrict__ label, int* __restrict__ counts, int* __restrict__ jlist) {
  int b = blockIdx.x;
  int tid = threadIdx.x;
  __shared__ int lab[L_];
  lab[tid] = label[b * L_ + tid];
  if (tid < NC_) counts[b * NC_ + tid] = 0;
  __syncthreads();
  int my = lab[tid];
  int rank = 0, cnt = 0;
  for (int j = 0; j < L_; ++j) {
    int e = (lab[j] == my) ? 1 : 0;
    cnt += e;
    if (j < tid) rank += e;
  }
  jlist[(b * NC_ + my) * L_ + rank] = tid;
  if (rank == 0) counts[b * NC_ + my] = cnt;
}

// ---------------- Kernel B: S = sum_v key; also bf16 hi/lo of S -------------
__global__ __launch_bounds__(256) void sumkey_kernel(
    const float* __restrict__ key, float* __restrict__ S,
    unsigned short* __restrict__ Sh, unsigned short* __restrict__ Sl, int do16) {
  int idx = blockIdx.x * 256 + threadIdx.x;  // over B*L*32 float4 groups
  int d4 = idx & 31;
  int bj = idx >> 5;
  const float4* kp = (const float4*)(key + (size_t)bj * V_ * D_) + d4;
  float4 s = make_float4(0.f, 0.f, 0.f, 0.f);
#pragma unroll 8
  for (int v = 0; v < V_; ++v) {
    float4 x = kp[v * 32];
    s.x += x.x; s.y += x.y; s.z += x.z; s.w += x.w;
  }
  *((float4*)S + idx) = s;
  if (do16) {
    unsigned short h0 = f2bf(s.x), h1 = f2bf(s.y), h2 = f2bf(s.z), h3 = f2bf(s.w);
    *((ushort4*)Sh + idx) = make_ushort4(h0, h1, h2, h3);
    *((ushort4*)Sl + idx) = make_ushort4(
        f2bf(s.x - bf2f(h0)), f2bf(s.y - bf2f(h1)),
        f2bf(s.z - bf2f(h2)), f2bf(s.w - bf2f(h3)));
  }
}

// ---------------- P-slab prefix (compressed allocation + capacity gate) -----
__global__ void pbase_kernel(const int* __restrict__ counts,
                             int* __restrict__ pbase, int* __restrict__ pflag,
                             long long cap, int force) {
  if (blockIdx.x == 0 && threadIdx.x == 0) {
    long long acc = 0;
    for (int bc = 0; bc < B_ * NC_; ++bc) {
      int n = counts[bc];
      int np = (n + 31) & ~31;
      long long sz = (n > 0 && n <= NMAX) ? (long long)V_ * n * np : 0;
      int bad = (force || n == 0 || n > NMAX || acc + sz > cap) ? 1 : 0;
      pflag[bc] = bad;
      pbase[bc] = (int)acc;
      if (!bad) acc += sz;
    }
  }
}

// ---------------- Kernel 2: QK^T (bf16 split MFMA) + softmax -> P -----------
// block = (b, c, i). 4 waves, wave w owns attention-k rows [16w,16w+16).
// A = q rows (hi/lo bf16 split), B = S^T tiles loaded straight from global.
__global__ __launch_bounds__(256) void qk_softmax_kernel(
    const float* __restrict__ q, const unsigned short* __restrict__ Sh,
    const unsigned short* __restrict__ Sl,
    const int* __restrict__ counts, const int* __restrict__ jlist,
    const int* __restrict__ pbase, const int* __restrict__ pflag,
    unsigned short* __restrict__ P) {
  int bid = blockIdx.x;
  int ii = bid & (NMAX - 1);
  int c = (bid >> 7) & (NC_ - 1);
  int b = bid >> 10;
  int bc = b * NC_ + c;
  int n = counts[bc];
  if (n > NMAX || ii >= n || pflag[bc]) return;
  int np = (n + 31) & ~31;
  int nt = np >> 4;
  int base = pbase[bc];

  int tid = threadIdx.x;
  int w = tid >> 6, l = tid & 63, lr = l & 15, lg = l >> 4;

  __shared__ int jl[NMAX];
  for (int j = tid; j < np; j += 256) jl[j] = jlist[bc * L_ + min(j, n - 1)];
  __syncthreads();

  int i = jlist[bc * L_ + ii];

  // A frags: row (=attn k) = 16w+lr, k-dim elems (lg*8..+8) per 32-chunk
  const float* qb = q + ((size_t)(b * L_ + i) * V_ + 16 * w + lr) * D_ + lg * 8;
  s16x8 Ah[4], Al[4];
#pragma unroll
  for (int kk = 0; kk < 4; ++kk) {
    float4 x0 = *(const float4*)(qb + kk * 32);
    float4 x1 = *(const float4*)(qb + kk * 32 + 4);
    float xs[8] = {x0.x, x0.y, x0.z, x0.w, x1.x, x1.y, x1.z, x1.w};
#pragma unroll
    for (int e = 0; e < 8; ++e) {
      unsigned short h = f2bf(xs[e]);
      Ah[kk][e] = (short)h;
      Al[kk][e] = (short)f2bf(xs[e] - bf2f(h));
    }
  }

  f32x4 cacc[8];
#pragma unroll
  for (int jt = 0; jt < 8; ++jt) {
    if (jt < nt) {
      int jrow = jl[jt * 16 + lr];  // B col = j = jt*16+lr (clamped)
      const unsigned short* sbh = Sh + (size_t)(b * L_ + jrow) * D_ + lg * 8;
      const unsigned short* sbl = Sl + (size_t)(b * L_ + jrow) * D_ + lg * 8;
      f32x4 acc = {0.f, 0.f, 0.f, 0.f};
#pragma unroll
      for (int kk = 0; kk < 4; ++kk) {
        s16x8 bh = *(const s16x8*)(sbh + kk * 32);
        s16x8 bl = *(const s16x8*)(sbl + kk * 32);
        acc = __builtin_amdgcn_mfma_f32_16x16x32_bf16(Ah[kk], bh, acc, 0, 0, 0);
        acc = __builtin_amdgcn_mfma_f32_16x16x32_bf16(Al[kk], bh, acc, 0, 0, 0);
        acc = __builtin_amdgcn_mfma_f32_16x16x32_bf16(Ah[kk], bl, acc, 0, 0, 0);
      }
      cacc[jt] = acc;
    }
  }

  // softmax per C-row (attn k = 16w + lg*4 + reg); row spans 16 lanes (cols)
#pragma unroll
  for (int reg = 0; reg < 4; ++reg) {
    float sv[8];
    float mx = -3.0e38f;
#pragma unroll
    for (int jt = 0; jt < 8; ++jt) {
      if (jt < nt) {
        float x = ((jt * 16 + lr) < n) ? cacc[jt][reg] * SCALE : -3.0e38f;
        sv[jt] = x;
        mx = fmaxf(mx, x);
      }
    }
    mx = fmaxf(mx, __shfl_xor(mx, 1));
    mx = fmaxf(mx, __shfl_xor(mx, 2));
    mx = fmaxf(mx, __shfl_xor(mx, 4));
    mx = fmaxf(mx, __shfl_xor(mx, 8));
    float sum = 0.f;
#pragma unroll
    for (int jt = 0; jt < 8; ++jt) {
      if (jt < nt) {
        float p = __expf(sv[jt] - mx);
        p = ((jt * 16 + lr) < n) ? p : 0.f;
        sv[jt] = p;
        sum += p;
      }
    }
    sum += __shfl_xor(sum, 1);
    sum += __shfl_xor(sum, 2);
    sum += __shfl_xor(sum, 4);
    sum += __shfl_xor(sum, 8);
    float inv = 1.0f / sum;
    int krow = 16 * w + lg * 4 + reg;
    int rb = base + (krow * n + ii) * np;
#pragma unroll
    for (int jt = 0; jt < 8; ++jt)
      if (jt < nt) P[rb + jt * 16 + lr] = f2bf(sv[jt] * inv);
  }
}

// ---------------- Kernel 3: out_k = P_k (bf16) x V_k (bf16 split) -----------
// block = (b, c, k). V^T staged in LDS (padded stride np+8: b128 reads stay
// 16B-aligned). Two d-halves sequentially to keep LDS at ~35 KB.
__global__ __launch_bounds__(256) void pv_kernel(
    const float* __restrict__ vg, const int* __restrict__ counts,
    const int* __restrict__ jlist, const int* __restrict__ pbase,
    const int* __restrict__ pflag, const unsigned short* __restrict__ P,
    float* __restrict__ out) {
  int bid = blockIdx.x;
  int k = bid & (V_ - 1);
  int c = (bid >> 6) & (NC_ - 1);
  int b = bid >> 9;
  int bc = b * NC_ + c;
  int n = counts[bc];
  if (n == 0 || n > NMAX || pflag[bc]) return;
  int np = (n + 31) & ~31;
  int ktn = np >> 5;
  int stride = np + NPAD;
  int base = pbase[bc];
  int mt = (n + 15) >> 4;

  int tid = threadIdx.x;
  int w = tid >> 6, l = tid & 63, lr = l & 15, lg = l >> 4;

  __shared__ int jl[NMAX];
  __shared__ __align__(16) unsigned short Vth[64 * (NMAX + NPAD)];
  __shared__ __align__(16) unsigned short Vtl[64 * (NMAX + NPAD)];

  for (int j = tid; j < np; j += 256) jl[j] = jlist[bc * L_ + min(j, n - 1)];
  __syncthreads();

  for (int dh = 0; dh < 2; ++dh) {
    if (dh) __syncthreads();  // all reads of previous half done
    // stage V^T for d in [64dh, 64dh+64): 16 float4-cols x 16 rows per pass
    int d4 = tid & 15;
    for (int j0 = 0; j0 < np; j0 += 16) {
      int jj = j0 + (tid >> 4);
      float4 x = make_float4(0.f, 0.f, 0.f, 0.f);
      if (jj < n)
        x = *(const float4*)(vg + ((size_t)(b * L_ + jl[jj]) * V_ + k) * D_
                             + dh * 64 + d4 * 4);
      float xs[4] = {x.x, x.y, x.z, x.w};
#pragma unroll
      for (int e = 0; e < 4; ++e) {
        unsigned short h = f2bf(xs[e]);
        Vth[(d4 * 4 + e) * stride + jj] = h;
        Vtl[(d4 * 4 + e) * stride + jj] = f2bf(xs[e] - bf2f(h));
      }
    }
    __syncthreads();

    // B frags: wave w -> d-tile w of this half (col d = dh*64 + w*16 + lr)
    s16x8 bh[4], bl[4];
#pragma unroll
    for (int kt = 0; kt < 4; ++kt) {
      if (kt < ktn) {
        int off = (w * 16 + lr) * stride + kt * 32 + lg * 8;
        bh[kt] = *(const s16x8*)(Vth + off);
        bl[kt] = *(const s16x8*)(Vtl + off);
      }
    }

#pragma unroll
    for (int mi = 0; mi < 8; ++mi) {
      if (mi < mt) {
        int irow = min(mi * 16 + lr, n - 1);
        const unsigned short* pa = P + base + ((size_t)k * n + irow) * np + lg * 8;
        f32x4 acc = {0.f, 0.f, 0.f, 0.f};
#pragma unroll
        for (int kt = 0; kt < 4; ++kt) {
          if (kt < ktn) {
            s16x8 af = *(const s16x8*)(pa + kt * 32);
            acc = __builtin_amdgcn_mfma_f32_16x16x32_bf16(af, bh[kt], acc, 0, 0, 0);
            acc = __builtin_amdgcn_mfma_f32_16x16x32_bf16(af, bl[kt], acc, 0, 0, 0);
          }
        }
#pragma unroll
        for (int reg = 0; reg < 4; ++reg) {
          int i = mi * 16 + lg * 4 + reg;
          if (i < n)
            out[((size_t)(b * L_ + jl[i]) * V_ + k) * D_ + dh * 64 + w * 16 + lr]
                = acc[reg];
        }
      }
    }
  }
}

// ---------------- Fallback (proven VALU flash kernel, gated) ----------------
__global__ __launch_bounds__(FB_THREADS, 2) void clustered_attn_kernel(
    const float* __restrict__ q, const float* __restrict__ value,
    const float* __restrict__ S, const int* __restrict__ counts,
    const int* __restrict__ jlist, const int* __restrict__ pflag, int force,
    float* __restrict__ out) {
  int bid = blockIdx.x;
  int k = bid & (V_ - 1);
  int c = (bid >> 6) & (NC_ - 1);
  int b = (bid >> 9) & (B_ - 1);
  int itile = bid >> 10;
  int bc = b * NC_ + c;
  int n = counts[bc];
  if (!(force || n > NMAX || pflag[bc])) return;  // handled by MFMA path
  int it0 = itile * FB_IT;
  if (it0 >= n) return;

  int tid = threadIdx.x;
  int dh = tid & 7;
  int sl = tid >> 3;

  __shared__ int jl[L_];
  __shared__ float S_t[FB_JT][D_];
  __shared__ float V_t[FB_JT][D_];

  for (int j = tid; j < n; j += FB_THREADS) jl[j] = jlist[bc * L_ + j];
  __syncthreads();

  bool act[4];
  float4 q4[4][4];
#pragma unroll
  for (int r = 0; r < 4; ++r) {
    int row = it0 + sl + 16 * r;
    act[r] = row < n;
    int i = jl[act[r] ? row : it0];
    const float* qrow = q + (size_t)((b * L_ + i) * V_ + k) * D_;
#pragma unroll
    for (int t = 0; t < 4; ++t) q4[r][t] = *(const float4*)(qrow + (dh + 8 * t) * 4);
  }

  float4 acc4[4][4];
#pragma unroll
  for (int r = 0; r < 4; ++r)
#pragma unroll
    for (int t = 0; t < 4; ++t) acc4[r][t] = make_float4(0.f, 0.f, 0.f, 0.f);
  float m[4], lden[4];
#pragma unroll
  for (int r = 0; r < 4; ++r) { m[r] = -INFINITY; lden[r] = 0.f; }

  const float4* S_t4 = (const float4*)&S_t[0][0];
  const float4* V_t4 = (const float4*)&V_t[0][0];

  for (int jt0 = 0; jt0 < n; jt0 += FB_JT) {
    int jn = min(FB_JT, n - jt0);
    __syncthreads();
#pragma unroll
    for (int rep = 0; rep < 2; ++rep) {
      int idx = tid + rep * FB_THREADS;
      int jj = idx >> 5;
      int d4 = idx & 31;
      int j = jl[jt0 + min(jj, jn - 1)];
      size_t rowbase = (size_t)(b * L_ + j);
      ((float4*)&S_t[0][0])[idx] = *(const float4*)(S + rowbase * D_ + d4 * 4);
      ((float4*)&V_t[0][0])[idx] =
          *(const float4*)(value + (rowbase * V_ + k) * D_ + d4 * 4);
    }
    __syncthreads();

    float s[4][FB_JT];
#pragma unroll
    for (int r = 0; r < 4; ++r)
#pragma unroll
      for (int jj = 0; jj < FB_JT; ++jj) s[r][jj] = 0.f;
#pragma unroll
    for (int t = 0; t < 4; ++t) {
#pragma unroll
      for (int jj = 0; jj < FB_JT; ++jj) {
        float4 sv = S_t4[jj * 32 + dh + 8 * t];
#pragma unroll
        for (int r = 0; r < 4; ++r) {
          float4 qv = q4[r][t];
          s[r][jj] = fmaf(qv.x, sv.x,
                     fmaf(qv.y, sv.y, fmaf(qv.z, sv.z, fmaf(qv.w, sv.w, s[r][jj]))));
        }
      }
    }
#pragma unroll
    for (int r = 0; r < 4; ++r)
#pragma unroll
      for (int jj = 0; jj < FB_JT; ++jj) {
        float v = s[r][jj] + __shfl_xor(s[r][jj], 1);
        v += __shfl_xor(v, 2);
        v += __shfl_xor(v, 4);
        s[r][jj] = v * SCALE;
      }
#pragma unroll
    for (int r = 0; r < 4; ++r) {
      float mnew = m[r];
#pragma unroll
      for (int jj = 0; jj < FB_JT; ++jj)
        if (jj < jn) mnew = fmaxf(mnew, s[r][jj]);
      float f = __expf(m[r] - mnew);
      m[r] = mnew;
#pragma unroll
      for (int t = 0; t < 4; ++t) {
        acc4[r][t].x *= f; acc4[r][t].y *= f;
        acc4[r][t].z *= f; acc4[r][t].w *= f;
      }
      float sum = 0.f;
#pragma unroll
      for (int jj = 0; jj < FB_JT; ++jj) {
        float p = (jj < jn) ? __expf(s[r][jj] - mnew) : 0.f;
        s[r][jj] = p;
        sum += p;
      }
      lden[r] = lden[r] * f + sum;
    }
#pragma unroll
    for (int t = 0; t < 4; ++t) {
#pragma unroll
      for (int jj = 0; jj < FB_JT; ++jj) {
        float4 vv = V_t4[jj * 32 + dh + 8 * t];
#pragma unroll
        for (int r = 0; r < 4; ++r) {
          float p = s[r][jj];
          acc4[r][t].x = fmaf(p, vv.x, acc4[r][t].x);
          acc4[r][t].y = fmaf(p, vv.y, acc4[r][t].y);
          acc4[r][t].z = fmaf(p, vv.z, acc4[r][t].z);
          acc4[r][t].w = fmaf(p, vv.w, acc4[r][t].w);
        }
      }
    }
  }

#pragma unroll
  for (int r = 0; r < 4; ++r) {
    if (act[r]) {
      int i = jl[it0 + sl + 16 * r];
      float inv = 1.0f / lden[r];
      float* op = out + (size_t)((b * L_ + i) * V_ + k) * D_;
#pragma unroll
      for (int t = 0; t < 4; ++t) {
        float4 o;
        o.x = acc4[r][t].x * inv;
        o.y = acc4[r][t].y * inv;
        o.z = acc4[r][t].z * inv;
        o.w = acc4[r][t].w * inv;
        *(float4*)(op + (dh + 8 * t) * 4) = o;
      }
    }
  }
}

extern "C" void kernel_launch(void* const* d_in, const int* in_sizes, int n_in,
                              void* d_out, int out_size, void* d_ws, size_t ws_size,
                              hipStream_t stream) {
  const float* q = (const float*)d_in[0];
  const float* key = (const float*)d_in[1];
  const float* value = (const float*)d_in[2];
  const int* label = (const int*)d_in[3];
  float* out = (float*)d_out;

  char* w8 = (char*)d_ws;
  int* counts = (int*)(w8 + 0);            // 64 B
  int* pbase = (int*)(w8 + 64);            // 64 B
  int* pflag = (int*)(w8 + 128);           // 64 B
  int* jlist = (int*)(w8 + 256);           // 32 KB
  float* S = (float*)(w8 + 33280);         // 512 KB
  unsigned short* Sh = (unsigned short*)(w8 + 557568);   // 256 KB
  unsigned short* Sl = (unsigned short*)(w8 + 819712);   // 256 KB
  unsigned short* P = (unsigned short*)(w8 + 1081856);   // rest

  long long cap = 0;
  if (ws_size > (size_t)1081856) cap = (long long)((ws_size - 1081856) / 2);
  int mfma_ok = (cap >= (1LL << 20)) ? 1 : 0;  // need ~2 MB+ of P space

  cluster_index_kernel<<<B_, L_, 0, stream>>>(label, counts, jlist);
  sumkey_kernel<<<(B_ * L_ * D_ / 4) / 256, 256, 0, stream>>>(key, S, Sh, Sl, mfma_ok);
  pbase_kernel<<<1, 64, 0, stream>>>(counts, pbase, pflag, cap, mfma_ok ? 0 : 1);
  if (mfma_ok) {
    qk_softmax_kernel<<<B_ * NC_ * NMAX, 256, 0, stream>>>(
        q, Sh, Sl, counts, jlist, pbase, pflag, P);
    pv_kernel<<<B_ * NC_ * V_, 256, 0, stream>>>(
        value, counts, jlist, pbase, pflag, P, out);
  }
  clustered_attn_kernel<<<B_ * NC_ * V_ * MAXIT, FB_THREADS, 0, stream>>>(
      q, value, S, counts, jlist, pflag, mfma_ok ? 0 : 1, out);
}

// Round 10
// 202.527 us; speedup vs baseline: 1.2277x; 1.0304x over previous
//
#include <hip/hip_runtime.h>
#include <math.h>

#define B_ 2
#define L_ 512
#define V_ 64
#define D_ 128
#define NC_ 8
#define NMAX 128
#define PSTR 136   // LDS row stride in shorts: 272B -> 2-way bank alias (free)
#define SCALE 0.08838834764831845f  // 1/sqrt(128)

#define FB_THREADS 128
#define FB_IT 64
#define FB_JT 8
#define MAXIT (L_ / FB_IT)

typedef short s16x8 __attribute__((ext_vector_type(8)));
typedef float f32x4 __attribute__((ext_vector_type(4)));

__device__ __forceinline__ unsigned short f2bf(float x) {
  unsigned int u = __float_as_uint(x);
  u += 0x7FFFu + ((u >> 16) & 1u);
  return (unsigned short)(u >> 16);
}
__device__ __forceinline__ float bf2f(unsigned short h) {
  return __uint_as_float((unsigned int)h << 16);
}

// ---------------- Kernel A: per-(b,cluster) member lists (deterministic) ----
__global__ __launch_bounds__(L_) void cluster_index_kernel(
    const int* __restrict__ label, int* __restrict__ counts, int* __restrict__ jlist) {
  int b = blockIdx.x;
  int tid = threadIdx.x;
  __shared__ int lab[L_];
  lab[tid] = label[b * L_ + tid];
  if (tid < NC_) counts[b * NC_ + tid] = 0;
  __syncthreads();
  int my = lab[tid];
  int rank = 0, cnt = 0;
  for (int j = 0; j < L_; ++j) {
    int e = (lab[j] == my) ? 1 : 0;
    cnt += e;
    if (j < tid) rank += e;
  }
  jlist[(b * NC_ + my) * L_ + rank] = tid;
  if (rank == 0) counts[b * NC_ + my] = cnt;
}

// ---------------- Kernel B: S = sum_v key (fp32 + bf16 hi/lo) ---------------
__global__ __launch_bounds__(256) void sumkey_kernel(
    const float* __restrict__ key, float* __restrict__ S,
    unsigned short* __restrict__ Sh, unsigned short* __restrict__ Sl) {
  int idx = blockIdx.x * 256 + threadIdx.x;  // over B*L*32 float4 groups
  int d4 = idx & 31;
  int bj = idx >> 5;
  const float4* kp = (const float4*)(key + (size_t)bj * V_ * D_) + d4;
  float4 s = make_float4(0.f, 0.f, 0.f, 0.f);
#pragma unroll 8
  for (int v = 0; v < V_; ++v) {
    float4 x = kp[v * 32];
    s.x += x.x; s.y += x.y; s.z += x.z; s.w += x.w;
  }
  *((float4*)S + idx) = s;
  unsigned short h0 = f2bf(s.x), h1 = f2bf(s.y), h2 = f2bf(s.z), h3 = f2bf(s.w);
  *((ushort4*)Sh + idx) = make_ushort4(h0, h1, h2, h3);
  *((ushort4*)Sl + idx) = make_ushort4(
      f2bf(s.x - bf2f(h0)), f2bf(s.y - bf2f(h1)),
      f2bf(s.z - bf2f(h2)), f2bf(s.w - bf2f(h3)));
}

// ---------------- Fused kernel: QK^T + softmax + PV per (b,c,k) -------------
// 256 thr = 4 waves; wave w owns i-row-tiles {w, w+4}. P lives only in LDS.
// V^T staged hi/lo per 64-d half (restage between halves). S gathered from
// global (L2-resident). All register arrays statically indexed.
__global__ __launch_bounds__(256, 2) void fused_attn_kernel(
    const float* __restrict__ q, const float* __restrict__ vg,
    const unsigned short* __restrict__ Sh, const unsigned short* __restrict__ Sl,
    const int* __restrict__ counts, const int* __restrict__ jlist,
    float* __restrict__ out) {
  int bid = blockIdx.x;
  int k = bid & (V_ - 1);
  int c = (bid >> 6) & (NC_ - 1);
  int b = bid >> 9;
  int bc = b * NC_ + c;
  int n = counts[bc];
  if (n == 0 || n > NMAX) return;
  int np32 = (n + 31) & ~31;   // j padded to 32 (PV k-dim chunks)
  int nt = np32 >> 4;          // j-tiles (<=8)
  int ktn = np32 >> 5;         // PV 32-chunks (<=4)
  int mtn = (n + 15) >> 4;     // i-row tiles (<=8)

  int tid = threadIdx.x;
  int w = tid >> 6;
  int l = tid & 63, lr = l & 15, lg = l >> 4;

  __shared__ int jl[NMAX];
  __shared__ __align__(16) unsigned short VTh[64][PSTR];  // 17 KB
  __shared__ __align__(16) unsigned short VTl[64][PSTR];  // 17 KB
  __shared__ __align__(16) unsigned short Pm[NMAX][PSTR]; // 34 KB

  for (int j = tid; j < np32; j += 256) jl[j] = jlist[bc * L_ + min(j, n - 1)];
  __syncthreads();

  // stage V^T (hi/lo) for a 64-wide d half starting at dbase
  auto stage_vt = [&](int dbase) {
    int d4 = tid & 15, jj = tid >> 4;
    for (int j = jj; j < np32; j += 16) {
      float4 x = *(const float4*)(vg + ((size_t)(b * L_ + jl[j]) * V_ + k) * D_
                                  + dbase + d4 * 4);
      float xs[4] = {x.x, x.y, x.z, x.w};
#pragma unroll
      for (int e = 0; e < 4; ++e) {
        unsigned short h = f2bf(xs[e]);
        VTh[d4 * 4 + e][j] = h;
        VTl[d4 * 4 + e][j] = f2bf(xs[e] - bf2f(h));
      }
    }
  };

  // PV for one 64-d half (reads Pm written by this wave)
  auto pv_half = [&](int dbase) {
    for (int mt = w; mt < mtn; mt += 4) {
#pragma unroll
      for (int dt = 0; dt < 4; ++dt) {
        f32x4 o = {0.f, 0.f, 0.f, 0.f};
#pragma unroll
        for (int kt = 0; kt < 4; ++kt) {
          if (kt < ktn) {
            s16x8 pa = *(const s16x8*)&Pm[mt * 16 + lr][kt * 32 + lg * 8];
            s16x8 vh = *(const s16x8*)&VTh[dt * 16 + lr][kt * 32 + lg * 8];
            s16x8 vl = *(const s16x8*)&VTl[dt * 16 + lr][kt * 32 + lg * 8];
            o = __builtin_amdgcn_mfma_f32_16x16x32_bf16(pa, vh, o, 0, 0, 0);
            o = __builtin_amdgcn_mfma_f32_16x16x32_bf16(pa, vl, o, 0, 0, 0);
          }
        }
#pragma unroll
        for (int reg = 0; reg < 4; ++reg) {
          int i = mt * 16 + lg * 4 + reg;
          if (i < n)
            out[((size_t)(b * L_ + jl[i]) * V_ + k) * D_ + dbase + dt * 16 + lr]
                = o[reg];
        }
      }
    }
  };

  stage_vt(0);
  __syncthreads();

  // ---- phase 1: per m-tile QK^T (split bf16 MFMA) + softmax -> Pm ----------
  for (int mt = w; mt < mtn; mt += 4) {
    const float* qb = q + ((size_t)(b * L_ + jl[mt * 16 + lr]) * V_ + k) * D_ + lg * 8;
    s16x8 Ah[4], Al[4];
#pragma unroll
    for (int kk = 0; kk < 4; ++kk) {
      float4 x0 = *(const float4*)(qb + kk * 32);
      float4 x1 = *(const float4*)(qb + kk * 32 + 4);
      float xs[8] = {x0.x, x0.y, x0.z, x0.w, x1.x, x1.y, x1.z, x1.w};
#pragma unroll
      for (int e = 0; e < 8; ++e) {
        unsigned short h = f2bf(xs[e]);
        Ah[kk][e] = (short)h;
        Al[kk][e] = (short)f2bf(xs[e] - bf2f(h));
      }
    }

    f32x4 acc[8];
#pragma unroll
    for (int jt = 0; jt < 8; ++jt) {
      if (jt < nt) {
        int jrow = jl[jt * 16 + lr];
        const unsigned short* sbh = Sh + (size_t)(b * L_ + jrow) * D_ + lg * 8;
        const unsigned short* sbl = Sl + (size_t)(b * L_ + jrow) * D_ + lg * 8;
        f32x4 a = {0.f, 0.f, 0.f, 0.f};
#pragma unroll
        for (int kk = 0; kk < 4; ++kk) {
          s16x8 bh = *(const s16x8*)(sbh + kk * 32);
          s16x8 bl = *(const s16x8*)(sbl + kk * 32);
          a = __builtin_amdgcn_mfma_f32_16x16x32_bf16(Ah[kk], bh, a, 0, 0, 0);
          a = __builtin_amdgcn_mfma_f32_16x16x32_bf16(Al[kk], bh, a, 0, 0, 0);
          a = __builtin_amdgcn_mfma_f32_16x16x32_bf16(Ah[kk], bl, a, 0, 0, 0);
        }
        acc[jt] = a;
      }
    }

    // softmax per C-row (row = mt*16 + lg*4 + reg spans 16 lanes = j-cols)
#pragma unroll
    for (int reg = 0; reg < 4; ++reg) {
      float sv[8];
      float mx = -3.0e38f;
#pragma unroll
      for (int jt = 0; jt < 8; ++jt) {
        if (jt < nt) {
          float x = ((jt * 16 + lr) < n) ? acc[jt][reg] * SCALE : -3.0e38f;
          sv[jt] = x;
          mx = fmaxf(mx, x);
        }
      }
      mx = fmaxf(mx, __shfl_xor(mx, 1));
      mx = fmaxf(mx, __shfl_xor(mx, 2));
      mx = fmaxf(mx, __shfl_xor(mx, 4));
      mx = fmaxf(mx, __shfl_xor(mx, 8));
      float sum = 0.f;
#pragma unroll
      for (int jt = 0; jt < 8; ++jt) {
        if (jt < nt) {
          float p = __expf(sv[jt] - mx);
          p = ((jt * 16 + lr) < n) ? p : 0.f;
          sv[jt] = p;
          sum += p;
        }
      }
      sum += __shfl_xor(sum, 1);
      sum += __shfl_xor(sum, 2);
      sum += __shfl_xor(sum, 4);
      sum += __shfl_xor(sum, 8);
      float inv = 1.0f / sum;
      int prow = mt * 16 + lg * 4 + reg;
#pragma unroll
      for (int jt = 0; jt < 8; ++jt)
        if (jt < nt) Pm[prow][jt * 16 + lr] = f2bf(sv[jt] * inv);
    }
  }

  // ---- PV d-half 0, restage V^T, PV d-half 1 -------------------------------
  pv_half(0);
  __syncthreads();
  stage_vt(64);
  __syncthreads();
  pv_half(64);
}

// ---------------- Fallback (proven VALU flash kernel) for n > NMAX ----------
__global__ __launch_bounds__(FB_THREADS, 2) void clustered_attn_kernel(
    const float* __restrict__ q, const float* __restrict__ value,
    const float* __restrict__ S, const int* __restrict__ counts,
    const int* __restrict__ jlist, float* __restrict__ out) {
  int bid = blockIdx.x;
  int k = bid & (V_ - 1);
  int c = (bid >> 6) & (NC_ - 1);
  int b = (bid >> 9) & (B_ - 1);
  int itile = bid >> 10;
  int bc = b * NC_ + c;
  int n = counts[bc];
  if (n <= NMAX) return;  // handled by fused MFMA kernel
  int it0 = itile * FB_IT;
  if (it0 >= n) return;

  int tid = threadIdx.x;
  int dh = tid & 7;
  int sl = tid >> 3;

  __shared__ int jl[L_];
  __shared__ float S_t[FB_JT][D_];
  __shared__ float V_t[FB_JT][D_];

  for (int j = tid; j < n; j += FB_THREADS) jl[j] = jlist[bc * L_ + j];
  __syncthreads();

  bool act[4];
  float4 q4[4][4];
#pragma unroll
  for (int r = 0; r < 4; ++r) {
    int row = it0 + sl + 16 * r;
    act[r] = row < n;
    int i = jl[act[r] ? row : it0];
    const float* qrow = q + (size_t)((b * L_ + i) * V_ + k) * D_;
#pragma unroll
    for (int t = 0; t < 4; ++t) q4[r][t] = *(const float4*)(qrow + (dh + 8 * t) * 4);
  }

  float4 acc4[4][4];
#pragma unroll
  for (int r = 0; r < 4; ++r)
#pragma unroll
    for (int t = 0; t < 4; ++t) acc4[r][t] = make_float4(0.f, 0.f, 0.f, 0.f);
  float m[4], lden[4];
#pragma unroll
  for (int r = 0; r < 4; ++r) { m[r] = -INFINITY; lden[r] = 0.f; }

  const float4* S_t4 = (const float4*)&S_t[0][0];
  const float4* V_t4 = (const float4*)&V_t[0][0];

  for (int jt0 = 0; jt0 < n; jt0 += FB_JT) {
    int jn = min(FB_JT, n - jt0);
    __syncthreads();
#pragma unroll
    for (int rep = 0; rep < 2; ++rep) {
      int idx = tid + rep * FB_THREADS;
      int jj = idx >> 5;
      int d4 = idx & 31;
      int j = jl[jt0 + min(jj, jn - 1)];
      size_t rowbase = (size_t)(b * L_ + j);
      ((float4*)&S_t[0][0])[idx] = *(const float4*)(S + rowbase * D_ + d4 * 4);
      ((float4*)&V_t[0][0])[idx] =
          *(const float4*)(value + (rowbase * V_ + k) * D_ + d4 * 4);
    }
    __syncthreads();

    float s[4][FB_JT];
#pragma unroll
    for (int r = 0; r < 4; ++r)
#pragma unroll
      for (int jj = 0; jj < FB_JT; ++jj) s[r][jj] = 0.f;
#pragma unroll
    for (int t = 0; t < 4; ++t) {
#pragma unroll
      for (int jj = 0; jj < FB_JT; ++jj) {
        float4 sv = S_t4[jj * 32 + dh + 8 * t];
#pragma unroll
        for (int r = 0; r < 4; ++r) {
          float4 qv = q4[r][t];
          s[r][jj] = fmaf(qv.x, sv.x,
                     fmaf(qv.y, sv.y, fmaf(qv.z, sv.z, fmaf(qv.w, sv.w, s[r][jj]))));
        }
      }
    }
#pragma unroll
    for (int r = 0; r < 4; ++r)
#pragma unroll
      for (int jj = 0; jj < FB_JT; ++jj) {
        float v = s[r][jj] + __shfl_xor(s[r][jj], 1);
        v += __shfl_xor(v, 2);
        v += __shfl_xor(v, 4);
        s[r][jj] = v * SCALE;
      }
#pragma unroll
    for (int r = 0; r < 4; ++r) {
      float mnew = m[r];
#pragma unroll
      for (int jj = 0; jj < FB_JT; ++jj)
        if (jj < jn) mnew = fmaxf(mnew, s[r][jj]);
      float f = __expf(m[r] - mnew);
      m[r] = mnew;
#pragma unroll
      for (int t = 0; t < 4; ++t) {
        acc4[r][t].x *= f; acc4[r][t].y *= f;
        acc4[r][t].z *= f; acc4[r][t].w *= f;
      }
      float sum = 0.f;
#pragma unroll
      for (int jj = 0; jj < FB_JT; ++jj) {
        float p = (jj < jn) ? __expf(s[r][jj] - mnew) : 0.f;
        s[r][jj] = p;
        sum += p;
      }
      lden[r] = lden[r] * f + sum;
    }
#pragma unroll
    for (int t = 0; t < 4; ++t) {
#pragma unroll
      for (int jj = 0; jj < FB_JT; ++jj) {
        float4 vv = V_t4[jj * 32 + dh + 8 * t];
#pragma unroll
        for (int r = 0; r < 4; ++r) {
          float p = s[r][jj];
          acc4[r][t].x = fmaf(p, vv.x, acc4[r][t].x);
          acc4[r][t].y = fmaf(p, vv.y, acc4[r][t].y);
          acc4[r][t].z = fmaf(p, vv.z, acc4[r][t].z);
          acc4[r][t].w = fmaf(p, vv.w, acc4[r][t].w);
        }
      }
    }
  }

#pragma unroll
  for (int r = 0; r < 4; ++r) {
    if (act[r]) {
      int i = jl[it0 + sl + 16 * r];
      float inv = 1.0f / lden[r];
      float* op = out + (size_t)((b * L_ + i) * V_ + k) * D_;
#pragma unroll
      for (int t = 0; t < 4; ++t) {
        float4 o;
        o.x = acc4[r][t].x * inv;
        o.y = acc4[r][t].y * inv;
        o.z = acc4[r][t].z * inv;
        o.w = acc4[r][t].w * inv;
        *(float4*)(op + (dh + 8 * t) * 4) = o;
      }
    }
  }
}

extern "C" void kernel_launch(void* const* d_in, const int* in_sizes, int n_in,
                              void* d_out, int out_size, void* d_ws, size_t ws_size,
                              hipStream_t stream) {
  const float* q = (const float*)d_in[0];
  const float* key = (const float*)d_in[1];
  const float* value = (const float*)d_in[2];
  const int* label = (const int*)d_in[3];
  float* out = (float*)d_out;

  char* w8 = (char*)d_ws;
  int* counts = (int*)(w8 + 0);                          // 64 B
  int* jlist = (int*)(w8 + 256);                         // 32 KB
  float* S = (float*)(w8 + 33280);                       // 512 KB
  unsigned short* Sh = (unsigned short*)(w8 + 557568);   // 256 KB
  unsigned short* Sl = (unsigned short*)(w8 + 819712);   // 256 KB

  cluster_index_kernel<<<B_, L_, 0, stream>>>(label, counts, jlist);
  sumkey_kernel<<<(B_ * L_ * D_ / 4) / 256, 256, 0, stream>>>(key, S, Sh, Sl);
  fused_attn_kernel<<<B_ * NC_ * V_, 256, 0, stream>>>(
      q, value, Sh, Sl, counts, jlist, out);
  clustered_attn_kernel<<<B_ * NC_ * V_ * MAXIT, FB_THREADS, 0, stream>>>(
      q, value, S, counts, jlist, out);
}

// Round 11
// 199.297 us; speedup vs baseline: 1.2476x; 1.0162x over previous
//
#include <hip/hip_runtime.h>
#include <math.h>

#define B_ 2
#define L_ 512
#define V_ 64
#define D_ 128
#define NC_ 8
#define NMAX 128
#define VSTR 40    // VT/P row stride in shorts (80 B): 16B-aligned b128 rows, ~2-way banks on reads
#define SCALE 0.08838834764831845f  // 1/sqrt(128)

#define FB_THREADS 128
#define FB_IT 64
#define FB_JT 8
#define MAXIT (L_ / FB_IT)

typedef short s16x8 __attribute__((ext_vector_type(8)));
typedef float f32x4 __attribute__((ext_vector_type(4)));

__device__ __forceinline__ unsigned short f2bf(float x) {
  unsigned int u = __float_as_uint(x);
  u += 0x7FFFu + ((u >> 16) & 1u);
  return (unsigned short)(u >> 16);
}
__device__ __forceinline__ float bf2f(unsigned short h) {
  return __uint_as_float((unsigned int)h << 16);
}

// ---- Kernel A: member lists + compact positions (deterministic) ------------
__global__ __launch_bounds__(L_) void cluster_index_kernel(
    const int* __restrict__ label, int* __restrict__ counts,
    int* __restrict__ jlist, int* __restrict__ posarr, int* __restrict__ bases) {
  int b = blockIdx.x;
  int tid = threadIdx.x;
  __shared__ int lab[L_];
  lab[tid] = label[b * L_ + tid];
  if (tid < NC_) counts[b * NC_ + tid] = 0;
  __syncthreads();
  int my = lab[tid];
  int rank = 0, cnt = 0, base = 0;
  for (int j = 0; j < L_; ++j) {
    int e = (lab[j] == my) ? 1 : 0;
    cnt += e;
    if (j < tid) rank += e;
    if (lab[j] < my) base++;
  }
  jlist[(b * NC_ + my) * L_ + rank] = tid;
  posarr[b * L_ + tid] = base + rank;   // compact row within batch
  if (rank == 0) { counts[b * NC_ + my] = cnt; bases[b * NC_ + my] = base; }
}

// ---- Kernel B: S = sum_v key; fp32 (fallback) + COMPACTED bf16 hi/lo -------
// block per (b,j): 256 thr = 128 d x 2 v-halves -> coalesced, 1024 blocks.
__global__ __launch_bounds__(256) void sumkey_kernel(
    const float* __restrict__ key, const int* __restrict__ posarr,
    float* __restrict__ S, unsigned short* __restrict__ Sch,
    unsigned short* __restrict__ Scl) {
  int bj = blockIdx.x;           // 0 .. B_*L_
  int tid = threadIdx.x;
  int d = tid & 127, vh = tid >> 7;
  const float* kp = key + (size_t)bj * V_ * D_ + vh * 32 * D_ + d;
  float s = 0.f;
#pragma unroll 8
  for (int v = 0; v < 32; ++v) s += kp[v * D_];
  __shared__ float buf[D_];
  if (vh) buf[d] = s;
  __syncthreads();
  if (!vh) {
    s += buf[d];
    S[(size_t)bj * D_ + d] = s;
    int b = bj >> 9;
    int crow = b * L_ + posarr[bj];
    unsigned short h = f2bf(s);
    Sch[(size_t)crow * D_ + d] = h;
    Scl[(size_t)crow * D_ + d] = f2bf(s - bf2f(h));
  }
}

// ---- Fused flash-chunk kernel: per (b,c,k,mhalf) ---------------------------
// 4 waves; wave w owns m-tile mhalf*4+w (16 i-rows). Per 32-j chunk:
// stage V^T hi/lo (full D) -> QK (compact contiguous S gathers, split bf16
// MFMA) -> online softmax in registers -> P via per-wave LDS transpose ->
// PV into register O accumulators. LDS 25.5 KB -> 4 blocks/CU.
__global__ __launch_bounds__(256, 4) void fused_attn_kernel(
    const float* __restrict__ q, const float* __restrict__ vg,
    const unsigned short* __restrict__ Sch, const unsigned short* __restrict__ Scl,
    const int* __restrict__ counts, const int* __restrict__ jlist,
    const int* __restrict__ bases, float* __restrict__ out) {
  int bid = blockIdx.x;
  int k = bid & (V_ - 1);
  int c = (bid >> 6) & (NC_ - 1);
  int b = (bid >> 9) & (B_ - 1);
  int mhalf = bid >> 10;
  int bc = b * NC_ + c;
  int n = counts[bc];
  if (n == 0 || n > NMAX || n <= mhalf * 64) return;
  int nch = (n + 31) >> 5;
  int mtn = (n + 15) >> 4;

  int tid = threadIdx.x;
  int w = tid >> 6, l = tid & 63, lr = l & 15, lg = l >> 4;
  int mt = mhalf * 4 + w;
  bool wact = mt < mtn;

  __shared__ int jl[NMAX];
  __shared__ __align__(16) unsigned short VTh[D_][VSTR];   // 10 KB
  __shared__ __align__(16) unsigned short VTl[D_][VSTR];   // 10 KB
  __shared__ __align__(16) unsigned short Pw[4][16][VSTR]; // 5 KB (per-wave)

  for (int j = tid; j < NMAX; j += 256) jl[j] = jlist[bc * L_ + min(j, n - 1)];
  __syncthreads();

  int cb = b * L_ + bases[bc];   // compact S row base for this cluster

  // persistent q A-frags (hi/lo): row i = jl[mt*16+lr], kdim d = kk*32+lg*8+e
  s16x8 Ah[4], Al[4];
  if (wact) {
    int iq = jl[min(mt * 16 + lr, n - 1)];
    const float* qb = q + ((size_t)(b * L_ + iq) * V_ + k) * D_ + lg * 8;
#pragma unroll
    for (int kk = 0; kk < 4; ++kk) {
      float4 x0 = *(const float4*)(qb + kk * 32);
      float4 x1 = *(const float4*)(qb + kk * 32 + 4);
      float xs[8] = {x0.x, x0.y, x0.z, x0.w, x1.x, x1.y, x1.z, x1.w};
#pragma unroll
      for (int e = 0; e < 8; ++e) {
        unsigned short h = f2bf(xs[e]);
        Ah[kk][e] = (short)h;
        Al[kk][e] = (short)f2bf(xs[e] - bf2f(h));
      }
    }
  }

  f32x4 aco[8];
#pragma unroll
  for (int dt = 0; dt < 8; ++dt) aco[dt] = (f32x4){0.f, 0.f, 0.f, 0.f};
  float mrow[4], lrow[4];
#pragma unroll
  for (int r = 0; r < 4; ++r) { mrow[r] = -INFINITY; lrow[r] = 0.f; }

  int d32 = tid & 31, jj8 = tid >> 5;   // stage mapping: 32 d-segs x 8 j-threads

  for (int ch = 0; ch < nch; ++ch) {
    __syncthreads();   // protect VT from previous chunk's readers
    // stage V^T chunk (rows j = ch*32 .. +32, clamped; full D, hi/lo)
#pragma unroll
    for (int it = 0; it < 4; ++it) {
      int jloc = jj8 + it * 8;
      int jg = jl[min(ch * 32 + jloc, n - 1)];
      float4 x = *(const float4*)(vg + ((size_t)(b * L_ + jg) * V_ + k) * D_ + d32 * 4);
      float xs[4] = {x.x, x.y, x.z, x.w};
#pragma unroll
      for (int e = 0; e < 4; ++e) {
        unsigned short h = f2bf(xs[e]);
        VTh[d32 * 4 + e][jloc] = h;
        VTl[d32 * 4 + e][jloc] = f2bf(xs[e] - bf2f(h));
      }
    }
    __syncthreads();

    if (wact) {
      // ---- QK: 2 j-tiles vs compact contiguous S rows ----
      f32x4 aq0 = {0.f, 0.f, 0.f, 0.f}, aq1 = {0.f, 0.f, 0.f, 0.f};
#pragma unroll
      for (int jt = 0; jt < 2; ++jt) {
        int jg = min(ch * 32 + jt * 16 + lr, n - 1);
        const unsigned short* sbh = Sch + (size_t)(cb + jg) * D_ + lg * 8;
        const unsigned short* sbl = Scl + (size_t)(cb + jg) * D_ + lg * 8;
        f32x4 a = {0.f, 0.f, 0.f, 0.f};
#pragma unroll
        for (int kk = 0; kk < 4; ++kk) {
          s16x8 bh = *(const s16x8*)(sbh + kk * 32);
          s16x8 bl = *(const s16x8*)(sbl + kk * 32);
          a = __builtin_amdgcn_mfma_f32_16x16x32_bf16(Ah[kk], bh, a, 0, 0, 0);
          a = __builtin_amdgcn_mfma_f32_16x16x32_bf16(Al[kk], bh, a, 0, 0, 0);
          a = __builtin_amdgcn_mfma_f32_16x16x32_bf16(Ah[kk], bl, a, 0, 0, 0);
        }
        if (jt == 0) aq0 = a; else aq1 = a;
      }
      // ---- online softmax per C-row (i = mt*16 + lg*4 + reg) ----
#pragma unroll
      for (int reg = 0; reg < 4; ++reg) {
        float x0 = (ch * 32 + lr < n) ? aq0[reg] * SCALE : -3.0e38f;
        float x1 = (ch * 32 + 16 + lr < n) ? aq1[reg] * SCALE : -3.0e38f;
        float cm = fmaxf(x0, x1);
        cm = fmaxf(cm, __shfl_xor(cm, 1));
        cm = fmaxf(cm, __shfl_xor(cm, 2));
        cm = fmaxf(cm, __shfl_xor(cm, 4));
        cm = fmaxf(cm, __shfl_xor(cm, 8));
        float mnew = fmaxf(mrow[reg], cm);
        float f = __expf(mrow[reg] - mnew);   // first chunk: exp(-inf)=0
        mrow[reg] = mnew;
        float p0 = __expf(x0 - mnew);
        float p1 = __expf(x1 - mnew);
        float sum = p0 + p1;
        sum += __shfl_xor(sum, 1);
        sum += __shfl_xor(sum, 2);
        sum += __shfl_xor(sum, 4);
        sum += __shfl_xor(sum, 8);
        lrow[reg] = lrow[reg] * f + sum;
#pragma unroll
        for (int dt = 0; dt < 8; ++dt) aco[dt][reg] *= f;
        Pw[w][lg * 4 + reg][lr] = f2bf(p0);        // C-layout -> A-layout
        Pw[w][lg * 4 + reg][16 + lr] = f2bf(p1);   // via wave-local scratch
      }
      // ---- PV: one K=32 step over the chunk ----
      s16x8 pa = *(const s16x8*)&Pw[w][lr][lg * 8];
#pragma unroll
      for (int dt = 0; dt < 8; ++dt) {
        s16x8 vh = *(const s16x8*)&VTh[dt * 16 + lr][lg * 8];
        s16x8 vl = *(const s16x8*)&VTl[dt * 16 + lr][lg * 8];
        aco[dt] = __builtin_amdgcn_mfma_f32_16x16x32_bf16(pa, vh, aco[dt], 0, 0, 0);
        aco[dt] = __builtin_amdgcn_mfma_f32_16x16x32_bf16(pa, vl, aco[dt], 0, 0, 0);
      }
    }
  }

  if (wact) {
#pragma unroll
    for (int reg = 0; reg < 4; ++reg) {
      float inv = 1.0f / lrow[reg];
      int ir = mt * 16 + lg * 4 + reg;
      if (ir < n) {
        float* op = out + ((size_t)(b * L_ + jl[ir]) * V_ + k) * D_ + lr;
#pragma unroll
        for (int dt = 0; dt < 8; ++dt) op[dt * 16] = aco[dt][reg] * inv;
      }
    }
  }
}

// ---- Fallback (proven VALU flash kernel) for n > NMAX ----------------------
__global__ __launch_bounds__(FB_THREADS, 2) void clustered_attn_kernel(
    const float* __restrict__ q, const float* __restrict__ value,
    const float* __restrict__ S, const int* __restrict__ counts,
    const int* __restrict__ jlist, float* __restrict__ out) {
  int bid = blockIdx.x;
  int k = bid & (V_ - 1);
  int c = (bid >> 6) & (NC_ - 1);
  int b = (bid >> 9) & (B_ - 1);
  int itile = bid >> 10;
  int bc = b * NC_ + c;
  int n = counts[bc];
  if (n <= NMAX) return;
  int it0 = itile * FB_IT;
  if (it0 >= n) return;

  int tid = threadIdx.x;
  int dh = tid & 7;
  int sl = tid >> 3;

  __shared__ int jl[L_];
  __shared__ float S_t[FB_JT][D_];
  __shared__ float V_t[FB_JT][D_];

  for (int j = tid; j < n; j += FB_THREADS) jl[j] = jlist[bc * L_ + j];
  __syncthreads();

  bool act[4];
  float4 q4[4][4];
#pragma unroll
  for (int r = 0; r < 4; ++r) {
    int row = it0 + sl + 16 * r;
    act[r] = row < n;
    int i = jl[act[r] ? row : it0];
    const float* qrow = q + (size_t)((b * L_ + i) * V_ + k) * D_;
#pragma unroll
    for (int t = 0; t < 4; ++t) q4[r][t] = *(const float4*)(qrow + (dh + 8 * t) * 4);
  }

  float4 acc4[4][4];
#pragma unroll
  for (int r = 0; r < 4; ++r)
#pragma unroll
    for (int t = 0; t < 4; ++t) acc4[r][t] = make_float4(0.f, 0.f, 0.f, 0.f);
  float m[4], lden[4];
#pragma unroll
  for (int r = 0; r < 4; ++r) { m[r] = -INFINITY; lden[r] = 0.f; }

  const float4* S_t4 = (const float4*)&S_t[0][0];
  const float4* V_t4 = (const float4*)&V_t[0][0];

  for (int jt0 = 0; jt0 < n; jt0 += FB_JT) {
    int jn = min(FB_JT, n - jt0);
    __syncthreads();
#pragma unroll
    for (int rep = 0; rep < 2; ++rep) {
      int idx = tid + rep * FB_THREADS;
      int jj = idx >> 5;
      int d4 = idx & 31;
      int j = jl[jt0 + min(jj, jn - 1)];
      size_t rowbase = (size_t)(b * L_ + j);
      ((float4*)&S_t[0][0])[idx] = *(const float4*)(S + rowbase * D_ + d4 * 4);
      ((float4*)&V_t[0][0])[idx] =
          *(const float4*)(value + (rowbase * V_ + k) * D_ + d4 * 4);
    }
    __syncthreads();

    float s[4][FB_JT];
#pragma unroll
    for (int r = 0; r < 4; ++r)
#pragma unroll
      for (int jj = 0; jj < FB_JT; ++jj) s[r][jj] = 0.f;
#pragma unroll
    for (int t = 0; t < 4; ++t) {
#pragma unroll
      for (int jj = 0; jj < FB_JT; ++jj) {
        float4 sv = S_t4[jj * 32 + dh + 8 * t];
#pragma unroll
        for (int r = 0; r < 4; ++r) {
          float4 qv = q4[r][t];
          s[r][jj] = fmaf(qv.x, sv.x,
                     fmaf(qv.y, sv.y, fmaf(qv.z, sv.z, fmaf(qv.w, sv.w, s[r][jj]))));
        }
      }
    }
#pragma unroll
    for (int r = 0; r < 4; ++r)
#pragma unroll
      for (int jj = 0; jj < FB_JT; ++jj) {
        float v = s[r][jj] + __shfl_xor(s[r][jj], 1);
        v += __shfl_xor(v, 2);
        v += __shfl_xor(v, 4);
        s[r][jj] = v * SCALE;
      }
#pragma unroll
    for (int r = 0; r < 4; ++r) {
      float mnew = m[r];
#pragma unroll
      for (int jj = 0; jj < FB_JT; ++jj)
        if (jj < jn) mnew = fmaxf(mnew, s[r][jj]);
      float f = __expf(m[r] - mnew);
      m[r] = mnew;
#pragma unroll
      for (int t = 0; t < 4; ++t) {
        acc4[r][t].x *= f; acc4[r][t].y *= f;
        acc4[r][t].z *= f; acc4[r][t].w *= f;
      }
      float sum = 0.f;
#pragma unroll
      for (int jj = 0; jj < FB_JT; ++jj) {
        float p = (jj < jn) ? __expf(s[r][jj] - mnew) : 0.f;
        s[r][jj] = p;
        sum += p;
      }
      lden[r] = lden[r] * f + sum;
    }
#pragma unroll
    for (int t = 0; t < 4; ++t) {
#pragma unroll
      for (int jj = 0; jj < FB_JT; ++jj) {
        float4 vv = V_t4[jj * 32 + dh + 8 * t];
#pragma unroll
        for (int r = 0; r < 4; ++r) {
          float p = s[r][jj];
          acc4[r][t].x = fmaf(p, vv.x, acc4[r][t].x);
          acc4[r][t].y = fmaf(p, vv.y, acc4[r][t].y);
          acc4[r][t].z = fmaf(p, vv.z, acc4[r][t].z);
          acc4[r][t].w = fmaf(p, vv.w, acc4[r][t].w);
        }
      }
    }
  }

#pragma unroll
  for (int r = 0; r < 4; ++r) {
    if (act[r]) {
      int i = jl[it0 + sl + 16 * r];
      float inv = 1.0f / lden[r];
      float* op = out + (size_t)((b * L_ + i) * V_ + k) * D_;
#pragma unroll
      for (int t = 0; t < 4; ++t) {
        float4 o;
        o.x = acc4[r][t].x * inv;
        o.y = acc4[r][t].y * inv;
        o.z = acc4[r][t].z * inv;
        o.w = acc4[r][t].w * inv;
        *(float4*)(op + (dh + 8 * t) * 4) = o;
      }
    }
  }
}

extern "C" void kernel_launch(void* const* d_in, const int* in_sizes, int n_in,
                              void* d_out, int out_size, void* d_ws, size_t ws_size,
                              hipStream_t stream) {
  const float* q = (const float*)d_in[0];
  const float* key = (const float*)d_in[1];
  const float* value = (const float*)d_in[2];
  const int* label = (const int*)d_in[3];
  float* out = (float*)d_out;

  char* w8 = (char*)d_ws;
  int* counts = (int*)(w8 + 0);                           // 64 B
  int* bases = (int*)(w8 + 64);                           // 64 B
  int* posarr = (int*)(w8 + 256);                         // 4 KB
  int* jlist = (int*)(w8 + 4352);                         // 32 KB
  float* S = (float*)(w8 + 37120);                        // 512 KB
  unsigned short* Sch = (unsigned short*)(w8 + 561408);   // 256 KB (compact)
  unsigned short* Scl = (unsigned short*)(w8 + 823552);   // 256 KB (compact)

  cluster_index_kernel<<<B_, L_, 0, stream>>>(label, counts, jlist, posarr, bases);
  sumkey_kernel<<<B_ * L_, 256, 0, stream>>>(key, posarr, S, Sch, Scl);
  fused_attn_kernel<<<B_ * NC_ * V_ * 2, 256, 0, stream>>>(
      q, value, Sch, Scl, counts, jlist, bases, out);
  clustered_attn_kernel<<<B_ * NC_ * V_ * MAXIT, FB_THREADS, 0, stream>>>(
      q, value, S, counts, jlist, out);
}